// Round 3
// baseline (403.661 us; speedup 1.0000x reference)
//
#include <hip/hip_runtime.h>
#include <math.h>

// Problem constants
#define B 8192
#define E 1024
#define D 384
#define H 64
#define R 8
#define NCHUNK 16     // chunks per (sample,k) row
#define CHUNK_E 64    // e's per chunk

// ws byte offsets (total 7,536,896 B)
#define WS_COUNTS   0u        // int[8]
#define WS_CURSORS  32u       // int[8]
#define WS_PS       64u       // float[8]
#define WS_OFFSETS  96u       // int[8]
#define WS_TOP2     256u      // int2[B]        -> 65792
#define WS_GW       65792u    // float2[B]      -> 131328
#define WS_LIST     131328u   // int[2B]        -> 196864
#define WS_EVN      196864u   // float[R*E*H]   -> 2294016  (2 MB)
#define WS_XUN      2294016u  // float[2B*H]    -> 6488320  (4 MB), row = b*2+k
#define WS_C        6488320u  // float[2B*16]   -> 7536896  (1 MB)

// ---------------- gate: logits, softmax probs (aux), top-2, gate weights ----
__global__ __launch_bounds__(256) void k_gate(
    const float* __restrict__ x, const float* __restrict__ gate_w,
    const float* __restrict__ gate_b, int2* __restrict__ top2,
    float2* __restrict__ gwv, int* __restrict__ counts, float* __restrict__ ps)
{
  __shared__ float gwl[D * R];
  __shared__ float psl[R];
  __shared__ int   cl[R];
  int tid = threadIdx.x;
  for (int i = tid; i < D * R; i += 256) gwl[i] = gate_w[i];
  if (tid < R) { psl[tid] = 0.f; cl[tid] = 0; }
  __syncthreads();

  int b = min(blockIdx.x * 256 + tid, B - 1);
  float acc[R];
#pragma unroll
  for (int r = 0; r < R; ++r) acc[r] = gate_b[r];
  const float* xp = x + (size_t)b * D;
  for (int d = 0; d < D; ++d) {
    float xv = xp[d];
#pragma unroll
    for (int r = 0; r < R; ++r) acc[r] = fmaf(xv, gwl[d * R + r], acc[r]);
  }
  // top-2 (ties -> lower index, matches lax.top_k)
  int i0 = 0; float v0 = acc[0];
#pragma unroll
  for (int r = 1; r < R; ++r) if (acc[r] > v0) { v0 = acc[r]; i0 = r; }
  int i1 = (i0 == 0) ? 1 : 0; float v1 = acc[i1];
#pragma unroll
  for (int r = 0; r < R; ++r)
    if (r != i0 && acc[r] > v1) { v1 = acc[r]; i1 = r; }
  // softmax probs for aux loss
  float se = 0.f; float pr[R];
#pragma unroll
  for (int r = 0; r < R; ++r) { pr[r] = expf(acc[r] - v0); se += pr[r]; }
  float inv = 1.f / se;
#pragma unroll
  for (int r = 0; r < R; ++r) atomicAdd(&psl[r], pr[r] * inv);
  atomicAdd(&cl[i0], 1); atomicAdd(&cl[i1], 1);
  // gate weights = softmax([v0, v1]) (v0 >= v1, no overflow)
  float e10 = expf(v1 - v0);
  float g0 = 1.f / (1.f + e10);
  float g1 = e10 / (1.f + e10);
  top2[b] = make_int2(i0, i1);
  gwv[b]  = make_float2(g0, g1);
  __syncthreads();
  if (tid < R) { atomicAdd(&ps[tid], psl[tid]); atomicAdd(&counts[tid], cl[tid]); }
}

// ---------------- offsets scan + aux loss ----------------------------------
__global__ void k_combine(const int* __restrict__ counts, const float* __restrict__ ps,
                          int* __restrict__ offsets, float* __restrict__ out_aux)
{
  if (threadIdx.x == 0 && blockIdx.x == 0) {
    int off = 0; float s = 0.f;
    for (int r = 0; r < R; ++r) {
      offsets[r] = off; off += counts[r];
      s += (ps[r] / (float)B) * ((float)counts[r] / (float)B);
    }
    out_aux[0] = (float)R * s * 0.05f;
  }
}

// ---------------- scatter samples into per-router lists --------------------
__global__ __launch_bounds__(256) void k_scatter(
    const int2* __restrict__ top2, const int* __restrict__ offsets,
    int* __restrict__ cursors, int* __restrict__ list)
{
  __shared__ int lc[R];
  __shared__ int lbase[R];
  int tid = threadIdx.x;
  if (tid < R) lc[tid] = 0;
  __syncthreads();
  int b = min(blockIdx.x * 256 + tid, B - 1);
  int2 t = top2[b];
  t.x &= 7; t.y &= 7;
  int p0 = atomicAdd(&lc[t.x], 1);
  int p1 = atomicAdd(&lc[t.y], 1);
  __syncthreads();
  if (tid < R) lbase[tid] = atomicAdd(&cursors[tid], lc[tid]);
  __syncthreads();
  int i0 = offsets[t.x] + lbase[t.x] + p0;
  int i1 = offsets[t.y] + lbase[t.y] + p1;
  list[min(i0, 2 * B - 1)] = b * 2 + 0;
  list[min(i1, 2 * B - 1)] = b * 2 + 1;
}

// ---------------- evn: l2norm(re @ Vw[r] + Vb[r]) --------------------------
// wave handles 8 e-rows; lane = h. 1024 waves total.
__global__ __launch_bounds__(256) void k_evn(
    const float* __restrict__ re, const float* __restrict__ Vw,
    const float* __restrict__ Vb, float* __restrict__ evn)
{
  int tid = threadIdx.x;
  int lane = tid & 63;
  int gid = blockIdx.x * 4 + (tid >> 6);   // 0..1023
  int r = (gid >> 7) & 7;
  int e0 = (gid & 127) * 8;
  float vb = Vb[r * H + lane];
  float acc[8];
#pragma unroll
  for (int j = 0; j < 8; ++j) acc[j] = vb;
  const float* vwp = Vw + (size_t)r * D * H + lane;
  const float* rep = re + (size_t)e0 * D;
  for (int d = 0; d < D; ++d) {
    float vw = vwp[(size_t)d * H];
#pragma unroll
    for (int j = 0; j < 8; ++j) acc[j] = fmaf(rep[(size_t)j * D + d], vw, acc[j]);
  }
#pragma unroll
  for (int j = 0; j < 8; ++j) {
    float ss = acc[j] * acc[j];
#pragma unroll
    for (int m = 1; m < 64; m <<= 1) ss += __shfl_xor(ss, m);
    float v = acc[j] / fmaxf(sqrtf(ss), 1e-12f);
    evn[(size_t)(r * E + e0 + j) * H + lane] = v;
  }
}

// ---------------- xun: l2norm(x[b] @ Uw[r] + Ub[r]) for listed entries -----
// wave handles 8 entries (same router); lane = h.
__global__ __launch_bounds__(256) void k_xun(
    const float* __restrict__ x, const float* __restrict__ Uw,
    const float* __restrict__ Ub, const int* __restrict__ list,
    const int* __restrict__ counts, const int* __restrict__ offsets,
    float* __restrict__ xun)
{
  int tid = threadIdx.x;
  int lane = tid & 63;
  int gid = blockIdx.x * 4 + (tid >> 6);   // 0..8191
  int r = (gid >> 10) & 7;
  int w = gid & 1023;
  int cnt = min(counts[r], B);
  int start = w * 8;
  if (cnt <= 0 || start >= cnt) return;
  int off = offsets[r];
  int ge[8];
#pragma unroll
  for (int j = 0; j < 8; ++j)
    ge[j] = list[min(off + min(start + j, cnt - 1), 2 * B - 1)] & (2 * B - 1);
  float ub = Ub[r * H + lane];
  float acc[8];
#pragma unroll
  for (int j = 0; j < 8; ++j) acc[j] = ub;
  const float* uwp = Uw + (size_t)r * D * H + lane;
  for (int d = 0; d < D; ++d) {
    float uw = uwp[(size_t)d * H];
#pragma unroll
    for (int j = 0; j < 8; ++j)
      acc[j] = fmaf(x[(size_t)(ge[j] >> 1) * D + d], uw, acc[j]);
  }
#pragma unroll
  for (int j = 0; j < 8; ++j) {
    float ss = acc[j] * acc[j];
#pragma unroll
    for (int m = 1; m < 64; m <<= 1) ss += __shfl_xor(ss, m);
    float v = acc[j] / fmaxf(sqrtf(ss), 1e-12f);
    if (start + j < cnt) xun[(size_t)ge[j] * H + lane] = v;
  }
}

// ---------------- pass1: grouped scores GEMM -> exp -> chunk sums ----------
// block = 128 entries x 512 e-half (4 stages of 128 e); 8x8 register tiles.
// XOR-swizzled LDS (no pad): conflict-free b32, 64 KB total.
__global__ __launch_bounds__(256) void k_pass1(
    const float* __restrict__ evn, const float* __restrict__ xun,
    const int* __restrict__ list, const int* __restrict__ counts,
    const int* __restrict__ offsets, float* __restrict__ C)
{
  int bid = blockIdx.x;
  int r = (bid >> 7) & 7;
  int rem = bid & 127;
  int tile = rem >> 1;
  int eh = rem & 1;
  int cnt = min(counts[r], B);
  if (cnt <= 0 || tile * 128 >= cnt) return;
  int off = offsets[r] + tile * 128;
  int n = min(128, cnt - tile * 128);

  __shared__ float xunL[128 * 64];
  __shared__ float evnL[128 * 64];
  int tid = threadIdx.x;

  for (int idx = tid; idx < 128 * 64; idx += 256) {
    int s = idx >> 6, h = idx & 63;
    int g = list[min(off + min(s, n - 1), 2 * B - 1)] & (2 * B - 1);
    xunL[s * 64 + (h ^ (s & 63))] = xun[(size_t)g * H + h];
  }
  int sg = tid >> 4, egr = tid & 15;

  for (int t = 0; t < 4; ++t) {
    int ebase = eh * 512 + t * 128;
    __syncthreads();
    for (int idx = tid; idx < 128 * 64; idx += 256) {
      int e = idx >> 6, h = idx & 63;
      evnL[e * 64 + (h ^ (e & 63))] = evn[(size_t)(r * E + ebase + e) * H + h];
    }
    __syncthreads();
    float acc[8][8];
#pragma unroll
    for (int i = 0; i < 8; ++i)
#pragma unroll
      for (int j = 0; j < 8; ++j) acc[i][j] = 0.f;
    for (int h = 0; h < 64; ++h) {
      float xv[8], ev[8];
#pragma unroll
      for (int i = 0; i < 8; ++i) {
        int s = sg * 8 + i;
        xv[i] = xunL[s * 64 + (h ^ (s & 63))];
      }
#pragma unroll
      for (int j = 0; j < 8; ++j) {
        int e = egr + 16 * j;
        ev[j] = evnL[e * 64 + (h ^ (e & 63))];
      }
#pragma unroll
      for (int i = 0; i < 8; ++i)
#pragma unroll
        for (int j = 0; j < 8; ++j) acc[i][j] = fmaf(xv[i], ev[j], acc[i][j]);
    }
    int cbase = (ebase >> 6);  // 2 chunks per stage
#pragma unroll
    for (int i = 0; i < 8; ++i) {
      float c0 = 0.f, c1 = 0.f;
#pragma unroll
      for (int j = 0; j < 4; ++j) c0 += expf(acc[i][j]);
#pragma unroll
      for (int j = 4; j < 8; ++j) c1 += expf(acc[i][j]);
#pragma unroll
      for (int m = 1; m < 16; m <<= 1) {
        c0 += __shfl_xor(c0, m);
        c1 += __shfl_xor(c1, m);
      }
      if (egr == 0) {
        int s = sg * 8 + i;
        if (s < n) {
          int g = list[min(off + s, 2 * B - 1)] & (2 * B - 1);
          C[(size_t)g * NCHUNK + cbase]     = c0;
          C[(size_t)g * NCHUNK + cbase + 1] = c1;
        }
      }
    }
  }
}

// ---------------- pass2: chunk-level inverse-CDF, recompute 1 chunk --------
// One wave per sample. Phase 1 (chunk CDF) is per-lane redundant sequential
// register math — wave-uniform by construction. Phase 2 uses one __shfl_up
// scan + one ballot. OUTPUT IS FLOAT32.
__global__ __launch_bounds__(256) void k_pass2(
    const float* __restrict__ evn, const float* __restrict__ xun,
    const float* __restrict__ C, const int2* __restrict__ top2,
    const float2* __restrict__ gwv, const float* __restrict__ rnd,
    float* __restrict__ out)
{
  int tid = threadIdx.x;
  int lane = tid & 63;
  int b = blockIdx.x * 4 + (tid >> 6);
  if (b >= B) return;
  int2 t2 = top2[b];
  t2.x &= 7; t2.y &= 7;
  float2 gw = gwv[b];
  float rv = rnd[b];

  // --- phase 1: redundant per-lane chunk CDF (broadcast scalar loads) ---
  const float* C0 = C + (size_t)(b * 2) * NCHUNK;
  const float* C1 = C + (size_t)(b * 2 + 1) * NCHUNK;
  float c0[NCHUNK], c1[NCHUNK];
  float S0 = 0.f, S1 = 0.f;
#pragma unroll
  for (int j = 0; j < NCHUNK; ++j) {
    c0[j] = C0[j]; c1[j] = C1[j];
    S0 += c0[j];   S1 += c1[j];
  }
  float a0 = gw.x / S0, a1 = gw.y / S1;
  int cstar = -1; float prefix = 0.f; float run = 0.f;
#pragma unroll
  for (int j = 0; j < NCHUNK; ++j) {
    float nrun = run + (c0[j] * a0 + c1[j] * a1);
    if (cstar < 0 && nrun > rv) { cstar = j; prefix = run; }
    run = nrun;
  }
  float rtgt = rv;
  if (cstar < 0) { cstar = 0; prefix = 0.f; rtgt = -1.0f; }  // ref: all-False argmax -> 0

  // --- phase 2: recompute chunk cstar exactly; lane = local e ---
  int e = cstar * CHUNK_E + lane;
  const float4* ev0 = (const float4*)(evn + (size_t)(t2.x * E + e) * H);
  const float4* ev1 = (const float4*)(evn + (size_t)(t2.y * E + e) * H);
  const float4* xu0 = (const float4*)(xun + (size_t)(b * 2) * H);
  const float4* xu1 = (const float4*)(xun + (size_t)(b * 2 + 1) * H);
  float d0 = 0.f, d1 = 0.f;
#pragma unroll
  for (int q = 0; q < 16; ++q) {
    float4 a = ev0[q]; float4 u = xu0[q];
    d0 += a.x * u.x + a.y * u.y + a.z * u.z + a.w * u.w;
    float4 c = ev1[q]; float4 v = xu1[q];
    d1 += c.x * v.x + c.y * v.y + c.z * v.z + c.w * v.w;
  }
  float rea = expf(d0) * a0 + expf(d1) * a1;   // rea_probs[b][e]
  float sc = rea;
#pragma unroll
  for (int d = 1; d < 64; d <<= 1) {
    float o = __shfl_up(sc, d);
    if (lane >= d) sc += o;
  }
  float cum = prefix + sc;
  unsigned long long m2 = __ballot(cum > rtgt);
  int estar = (m2 == 0ull) ? 63 : (int)__builtin_ctzll(m2);
  float p = __shfl(rea, estar);
  if (lane == 0) {
    int sel = cstar * CHUNK_E + estar;       // in [0, 1023]
    out[b]     = (float)sel;
    out[B + b] = logf(p);
  }
}

// ---------------------------------------------------------------------------
extern "C" void kernel_launch(void* const* d_in, const int* in_sizes, int n_in,
                              void* d_out, int out_size, void* d_ws, size_t ws_size,
                              hipStream_t stream)
{
  (void)in_sizes; (void)n_in; (void)out_size; (void)ws_size;
  const float* x      = (const float*)d_in[0];
  const float* re     = (const float*)d_in[1];
  const float* rnd    = (const float*)d_in[2];
  const float* gate_w = (const float*)d_in[3];
  const float* gate_b = (const float*)d_in[4];
  const float* Uw     = (const float*)d_in[5];
  const float* Ub     = (const float*)d_in[6];
  const float* Vw     = (const float*)d_in[7];
  const float* Vb     = (const float*)d_in[8];
  char* ws = (char*)d_ws;
  int*    counts  = (int*)(ws + WS_COUNTS);
  int*    cursors = (int*)(ws + WS_CURSORS);
  float*  ps      = (float*)(ws + WS_PS);
  int*    offsets = (int*)(ws + WS_OFFSETS);
  int2*   top2    = (int2*)(ws + WS_TOP2);
  float2* gwv     = (float2*)(ws + WS_GW);
  int*    list    = (int*)(ws + WS_LIST);
  float*  evn     = (float*)(ws + WS_EVN);
  float*  xun     = (float*)(ws + WS_XUN);
  float*  Cc      = (float*)(ws + WS_C);
  float* out = (float*)d_out;

  hipMemsetAsync(ws, 0, 256, stream);
  k_gate   <<<32,   256, 0, stream>>>(x, gate_w, gate_b, top2, gwv, counts, ps);
  k_combine<<<1,    64,  0, stream>>>(counts, ps, offsets, out + 2 * B);
  k_scatter<<<32,   256, 0, stream>>>(top2, offsets, cursors, list);
  k_evn    <<<256,  256, 0, stream>>>(re, Vw, Vb, evn);
  k_xun    <<<2048, 256, 0, stream>>>(x, Uw, Ub, list, counts, offsets, xun);
  k_pass1  <<<1024, 256, 0, stream>>>(evn, xun, list, counts, offsets, Cc);
  k_pass2  <<<2048, 256, 0, stream>>>(evn, xun, Cc, top2, gwv, rnd, out);
}

// Round 4
// 306.240 us; speedup vs baseline: 1.3181x; 1.3181x over previous
//
#include <hip/hip_runtime.h>
#include <math.h>

// Problem constants
#define B 8192
#define E 1024
#define D 384
#define H 64
#define R 8
#define NCHUNK 16
#define CHUNK_E 64

// ws byte offsets (total 7,536,896 B)
#define WS_COUNTS   0u
#define WS_CURSORS  32u
#define WS_PS       64u
#define WS_OFFSETS  96u
#define WS_TOP2     256u
#define WS_GW       65792u
#define WS_LIST     131328u
#define WS_EVN      196864u
#define WS_XUN      2294016u
#define WS_C        6488320u

// ---------------- gate: lane = (sample, router); LDS-transposed gate_w -----
// block = 256 threads = 32 samples; grid 256.
__global__ __launch_bounds__(256) void k_gate(
    const float* __restrict__ x, const float* __restrict__ gate_w,
    const float* __restrict__ gate_b, int2* __restrict__ top2,
    float2* __restrict__ gwv, int* __restrict__ counts, float* __restrict__ ps)
{
  __shared__ __align__(16) float gwT[R * 388];  // [r][k], pad 388 (16B-aligned rows)
  __shared__ float psl[R];
  __shared__ int   cl[R];
  int tid = threadIdx.x;
  for (int idx = tid; idx < D * R; idx += 256) {
    int k = idx >> 3, r = idx & 7;
    gwT[r * 388 + k] = gate_w[idx];
  }
  if (tid < R) { psl[tid] = 0.f; cl[tid] = 0; }
  __syncthreads();

  int l = tid & 63;
  int r = tid & 7;
  int b = blockIdx.x * 32 + (tid >> 3);          // < 8192
  float acc = gate_b[r];
  const float4* x4 = (const float4*)(x + (size_t)b * D);
  const float*  gr = gwT + r * 388;
#pragma unroll 4
  for (int q = 0; q < 96; ++q) {
    float4 xv = x4[q];                           // broadcast across 8 lanes
    float4 gv = *(const float4*)&gr[q * 4];      // ds_read_b128
    acc = fmaf(xv.x, gv.x, acc);
    acc = fmaf(xv.y, gv.y, acc);
    acc = fmaf(xv.z, gv.z, acc);
    acc = fmaf(xv.w, gv.w, acc);
  }
  // gather the 8 logits of this sample (lanes (l&~7)+0..7)
  float lv[R];
#pragma unroll
  for (int rr = 0; rr < R; ++rr) lv[rr] = __shfl(acc, (l & ~7) + rr);
  // redundant per-lane top-2 (ties -> lower index)
  int i0 = 0; float v0 = lv[0];
#pragma unroll
  for (int rr = 1; rr < R; ++rr) if (lv[rr] > v0) { v0 = lv[rr]; i0 = rr; }
  int i1 = (i0 == 0) ? 1 : 0; float v1 = lv[i1];
#pragma unroll
  for (int rr = 0; rr < R; ++rr)
    if (rr != i0 && lv[rr] > v1) { v1 = lv[rr]; i1 = rr; }
  float se = 0.f;
#pragma unroll
  for (int rr = 0; rr < R; ++rr) se += expf(lv[rr] - v0);
  float p = expf(acc - v0) / se;                 // this lane's router prob
  if (r == 0) {
    float e10 = expf(v1 - v0);
    top2[b] = make_int2(i0, i1);
    gwv[b]  = make_float2(1.f / (1.f + e10), e10 / (1.f + e10));
  }
  // reduce prob & top-k count over the 8 samples of this wave
  float pa = p;
  int   ca = (r == i0 ? 1 : 0) + (r == i1 ? 1 : 0);
#pragma unroll
  for (int m = 8; m < 64; m <<= 1) {
    pa += __shfl_xor(pa, m);
    ca += __shfl_xor(ca, m);
  }
  if (l < 8) { atomicAdd(&psl[r], pa); atomicAdd(&cl[r], ca); }
  __syncthreads();
  if (tid < R) { atomicAdd(&ps[tid], psl[tid]); atomicAdd(&counts[tid], cl[tid]); }
}

// ---------------- offsets scan + aux loss ----------------------------------
__global__ void k_combine(const int* __restrict__ counts, const float* __restrict__ ps,
                          int* __restrict__ offsets, float* __restrict__ out_aux)
{
  if (threadIdx.x == 0 && blockIdx.x == 0) {
    int off = 0; float s = 0.f;
    for (int r = 0; r < R; ++r) {
      offsets[r] = off; off += counts[r];
      s += (ps[r] / (float)B) * ((float)counts[r] / (float)B);
    }
    out_aux[0] = (float)R * s * 0.05f;
  }
}

// ---------------- scatter samples into per-router lists --------------------
__global__ __launch_bounds__(256) void k_scatter(
    const int2* __restrict__ top2, const int* __restrict__ offsets,
    int* __restrict__ cursors, int* __restrict__ list)
{
  __shared__ int lc[R];
  __shared__ int lbase[R];
  int tid = threadIdx.x;
  if (tid < R) lc[tid] = 0;
  __syncthreads();
  int b = min(blockIdx.x * 256 + tid, B - 1);
  int2 t = top2[b];
  t.x &= 7; t.y &= 7;
  int p0 = atomicAdd(&lc[t.x], 1);
  int p1 = atomicAdd(&lc[t.y], 1);
  __syncthreads();
  if (tid < R) lbase[tid] = atomicAdd(&cursors[tid], lc[tid]);
  __syncthreads();
  int i0 = offsets[t.x] + lbase[t.x] + p0;
  int i1 = offsets[t.y] + lbase[t.y] + p1;
  list[min(i0, 2 * B - 1)] = b * 2 + 0;
  list[min(i1, 2 * B - 1)] = b * 2 + 1;
}

// ---------------- evn: GEMM-tiled l2norm(re @ Vw[r] + Vb[r]) ---------------
// block: 64 rows x 64 h; K in 6 tiles of 64. A transposed+XOR-swizzled in LDS
// (ds_read_b128 in compute), W linear. thread: tc=tid&15 (4 cols), tr=tid>>4
// (4 rows). grid 128.
__global__ __launch_bounds__(256) void k_evn(
    const float* __restrict__ re, const float* __restrict__ Vw,
    const float* __restrict__ Vb, float* __restrict__ evn)
{
  __shared__ __align__(16) float At[64 * 64];
  __shared__ __align__(16) float Wt[64 * 64];
  int tid = threadIdx.x;
  int rg0 = blockIdx.x * 64;
  int r = rg0 >> 10;
  int e0 = rg0 & 1023;
  int tc = tid & 15, tr = tid >> 4;
  float4 vb = *(const float4*)(Vb + r * H + tc * 4);
  float acc[4][4];
#pragma unroll
  for (int i = 0; i < 4; ++i) { acc[i][0] = vb.x; acc[i][1] = vb.y; acc[i][2] = vb.z; acc[i][3] = vb.w; }

  int arow = tid >> 2, ac = tid & 3;
  const float4* Asrc = (const float4*)re + (size_t)(e0 + arow) * 96;
  const float4* Wsrc = (const float4*)Vw + (size_t)r * 6144;

  for (int kt = 0; kt < 6; ++kt) {
    __syncthreads();
#pragma unroll
    for (int i = 0; i < 4; ++i) {                 // A: load row-major, store transposed
      float4 v = Asrc[kt * 16 + ac + 4 * i];
      int colb = (ac + 4 * i) * 4;
#pragma unroll
      for (int m = 0; m < 4; ++m) {
        int col = colb + m;
        At[col * 64 + (arow ^ ((col & 15) << 2))] = ((const float*)&v)[m];
      }
    }
#pragma unroll
    for (int i = 0; i < 4; ++i) {                 // W: contiguous
      int idx = tid + 256 * i;
      *(float4*)&Wt[idx * 4] = Wsrc[kt * 1024 + idx];
    }
    __syncthreads();
    for (int k = 0; k < 64; ++k) {
      float4 a4 = *(const float4*)&At[k * 64 + ((tr * 4) ^ ((k & 15) << 2))];
      float4 w4 = *(const float4*)&Wt[k * 64 + tc * 4];
      const float* ap = (const float*)&a4;
      const float* wp = (const float*)&w4;
#pragma unroll
      for (int i = 0; i < 4; ++i)
#pragma unroll
        for (int j = 0; j < 4; ++j) acc[i][j] = fmaf(ap[i], wp[j], acc[i][j]);
    }
  }
#pragma unroll
  for (int i = 0; i < 4; ++i) {
    float ss = 0.f;
#pragma unroll
    for (int j = 0; j < 4; ++j) ss = fmaf(acc[i][j], acc[i][j], ss);
#pragma unroll
    for (int m = 1; m < 16; m <<= 1) ss += __shfl_xor(ss, m);
    float rn = 1.f / fmaxf(sqrtf(ss), 1e-12f);
    float4 o; o.x = acc[i][0] * rn; o.y = acc[i][1] * rn; o.z = acc[i][2] * rn; o.w = acc[i][3] * rn;
    *(float4*)(evn + (size_t)(r * E + e0 + tr * 4 + i) * H + tc * 4) = o;
  }
}

// ---------------- xun: GEMM-tiled l2norm(x[list] @ Uw[r] + Ub[r]) ----------
// same structure as k_evn with gathered A rows. grid 8*128 (early-exit).
__global__ __launch_bounds__(256) void k_xun(
    const float* __restrict__ x, const float* __restrict__ Uw,
    const float* __restrict__ Ub, const int* __restrict__ list,
    const int* __restrict__ counts, const int* __restrict__ offsets,
    float* __restrict__ xun)
{
  int r = blockIdx.x >> 7;
  int tile = blockIdx.x & 127;
  int cnt = min(counts[r], B);
  if (cnt <= 0 || tile * 64 >= cnt) return;
  int n = min(64, cnt - tile * 64);
  int base = offsets[r] + tile * 64;

  __shared__ __align__(16) float At[64 * 64];
  __shared__ __align__(16) float Wt[64 * 64];
  int tid = threadIdx.x;
  int tc = tid & 15, tr = tid >> 4;
  float4 ub = *(const float4*)(Ub + r * H + tc * 4);
  float acc[4][4];
#pragma unroll
  for (int i = 0; i < 4; ++i) { acc[i][0] = ub.x; acc[i][1] = ub.y; acc[i][2] = ub.z; acc[i][3] = ub.w; }

  int arow = tid >> 2, ac = tid & 3;
  int ga = list[min(base + min(arow, n - 1), 2 * B - 1)] & (2 * B - 1);
  const float4* Asrc = (const float4*)x + (size_t)(ga >> 1) * 96;
  const float4* Wsrc = (const float4*)Uw + (size_t)r * 6144;

  for (int kt = 0; kt < 6; ++kt) {
    __syncthreads();
#pragma unroll
    for (int i = 0; i < 4; ++i) {
      float4 v = Asrc[kt * 16 + ac + 4 * i];
      int colb = (ac + 4 * i) * 4;
#pragma unroll
      for (int m = 0; m < 4; ++m) {
        int col = colb + m;
        At[col * 64 + (arow ^ ((col & 15) << 2))] = ((const float*)&v)[m];
      }
    }
#pragma unroll
    for (int i = 0; i < 4; ++i) {
      int idx = tid + 256 * i;
      *(float4*)&Wt[idx * 4] = Wsrc[kt * 1024 + idx];
    }
    __syncthreads();
    for (int k = 0; k < 64; ++k) {
      float4 a4 = *(const float4*)&At[k * 64 + ((tr * 4) ^ ((k & 15) << 2))];
      float4 w4 = *(const float4*)&Wt[k * 64 + tc * 4];
      const float* ap = (const float*)&a4;
      const float* wp = (const float*)&w4;
#pragma unroll
      for (int i = 0; i < 4; ++i)
#pragma unroll
        for (int j = 0; j < 4; ++j) acc[i][j] = fmaf(ap[i], wp[j], acc[i][j]);
    }
  }
#pragma unroll
  for (int i = 0; i < 4; ++i) {
    int row = tr * 4 + i;
    float ss = 0.f;
#pragma unroll
    for (int j = 0; j < 4; ++j) ss = fmaf(acc[i][j], acc[i][j], ss);
#pragma unroll
    for (int m = 1; m < 16; m <<= 1) ss += __shfl_xor(ss, m);
    float rn = 1.f / fmaxf(sqrtf(ss), 1e-12f);
    if (row < n) {
      int g = list[min(base + row, 2 * B - 1)] & (2 * B - 1);
      float4 o; o.x = acc[i][0] * rn; o.y = acc[i][1] * rn; o.z = acc[i][2] * rn; o.w = acc[i][3] * rn;
      *(float4*)(xun + (size_t)g * H + tc * 4) = o;
    }
  }
}

// ---------------- pass1: grouped scores GEMM -> exp -> chunk sums ----------
__global__ __launch_bounds__(256) void k_pass1(
    const float* __restrict__ evn, const float* __restrict__ xun,
    const int* __restrict__ list, const int* __restrict__ counts,
    const int* __restrict__ offsets, float* __restrict__ C)
{
  int bid = blockIdx.x;
  int r = (bid >> 7) & 7;
  int rem = bid & 127;
  int tile = rem >> 1;
  int eh = rem & 1;
  int cnt = min(counts[r], B);
  if (cnt <= 0 || tile * 128 >= cnt) return;
  int off = offsets[r] + tile * 128;
  int n = min(128, cnt - tile * 128);

  __shared__ float xunL[128 * 64];
  __shared__ float evnL[128 * 64];
  int tid = threadIdx.x;

  for (int idx = tid; idx < 128 * 64; idx += 256) {
    int s = idx >> 6, h = idx & 63;
    int g = list[min(off + min(s, n - 1), 2 * B - 1)] & (2 * B - 1);
    xunL[s * 64 + (h ^ (s & 63))] = xun[(size_t)g * H + h];
  }
  int sg = tid >> 4, egr = tid & 15;

  for (int t = 0; t < 4; ++t) {
    int ebase = eh * 512 + t * 128;
    __syncthreads();
    for (int idx = tid; idx < 128 * 64; idx += 256) {
      int e = idx >> 6, h = idx & 63;
      evnL[e * 64 + (h ^ (e & 63))] = evn[(size_t)(r * E + ebase + e) * H + h];
    }
    __syncthreads();
    float acc[8][8];
#pragma unroll
    for (int i = 0; i < 8; ++i)
#pragma unroll
      for (int j = 0; j < 8; ++j) acc[i][j] = 0.f;
    for (int h = 0; h < 64; ++h) {
      float xv[8], ev[8];
#pragma unroll
      for (int i = 0; i < 8; ++i) {
        int s = sg * 8 + i;
        xv[i] = xunL[s * 64 + (h ^ (s & 63))];
      }
#pragma unroll
      for (int j = 0; j < 8; ++j) {
        int e = egr + 16 * j;
        ev[j] = evnL[e * 64 + (h ^ (e & 63))];
      }
#pragma unroll
      for (int i = 0; i < 8; ++i)
#pragma unroll
        for (int j = 0; j < 8; ++j) acc[i][j] = fmaf(xv[i], ev[j], acc[i][j]);
    }
    int cbase = (ebase >> 6);
#pragma unroll
    for (int i = 0; i < 8; ++i) {
      float c0 = 0.f, c1 = 0.f;
#pragma unroll
      for (int j = 0; j < 4; ++j) c0 += expf(acc[i][j]);
#pragma unroll
      for (int j = 4; j < 8; ++j) c1 += expf(acc[i][j]);
#pragma unroll
      for (int m = 1; m < 16; m <<= 1) {
        c0 += __shfl_xor(c0, m);
        c1 += __shfl_xor(c1, m);
      }
      if (egr == 0) {
        int s = sg * 8 + i;
        if (s < n) {
          int g = list[min(off + s, 2 * B - 1)] & (2 * B - 1);
          C[(size_t)g * NCHUNK + cbase]     = c0;
          C[(size_t)g * NCHUNK + cbase + 1] = c1;
        }
      }
    }
  }
}

// ---------------- pass2: chunk-level inverse-CDF, recompute 1 chunk --------
__global__ __launch_bounds__(256) void k_pass2(
    const float* __restrict__ evn, const float* __restrict__ xun,
    const float* __restrict__ C, const int2* __restrict__ top2,
    const float2* __restrict__ gwv, const float* __restrict__ rnd,
    float* __restrict__ out)
{
  int tid = threadIdx.x;
  int lane = tid & 63;
  int b = blockIdx.x * 4 + (tid >> 6);
  if (b >= B) return;
  int2 t2 = top2[b];
  t2.x &= 7; t2.y &= 7;
  float2 gw = gwv[b];
  float rv = rnd[b];

  // phase 1: redundant per-lane chunk CDF (float4 broadcast loads)
  const float4* C04 = (const float4*)(C + (size_t)(b * 2) * NCHUNK);
  const float4* C14 = (const float4*)(C + (size_t)(b * 2 + 1) * NCHUNK);
  float c0[NCHUNK], c1[NCHUNK];
#pragma unroll
  for (int q = 0; q < 4; ++q) {
    float4 v0 = C04[q], v1 = C14[q];
    c0[q*4+0]=v0.x; c0[q*4+1]=v0.y; c0[q*4+2]=v0.z; c0[q*4+3]=v0.w;
    c1[q*4+0]=v1.x; c1[q*4+1]=v1.y; c1[q*4+2]=v1.z; c1[q*4+3]=v1.w;
  }
  float S0 = 0.f, S1 = 0.f;
#pragma unroll
  for (int j = 0; j < NCHUNK; ++j) { S0 += c0[j]; S1 += c1[j]; }
  float a0 = gw.x / S0, a1 = gw.y / S1;
  int cstar = -1; float prefix = 0.f; float run = 0.f;
#pragma unroll
  for (int j = 0; j < NCHUNK; ++j) {
    float nrun = run + (c0[j] * a0 + c1[j] * a1);
    if (cstar < 0 && nrun > rv) { cstar = j; prefix = run; }
    run = nrun;
  }
  float rtgt = rv;
  if (cstar < 0) { cstar = 0; prefix = 0.f; rtgt = -1.0f; }

  // phase 2: recompute chunk cstar exactly; lane = local e
  int e = cstar * CHUNK_E + lane;
  const float4* ev0 = (const float4*)(evn + (size_t)(t2.x * E + e) * H);
  const float4* ev1 = (const float4*)(evn + (size_t)(t2.y * E + e) * H);
  const float4* xu0 = (const float4*)(xun + (size_t)(b * 2) * H);
  const float4* xu1 = (const float4*)(xun + (size_t)(b * 2 + 1) * H);
  float d0 = 0.f, d1 = 0.f;
#pragma unroll
  for (int q = 0; q < 16; ++q) {
    float4 a = ev0[q]; float4 u = xu0[q];
    d0 += a.x * u.x + a.y * u.y + a.z * u.z + a.w * u.w;
    float4 c = ev1[q]; float4 v = xu1[q];
    d1 += c.x * v.x + c.y * v.y + c.z * v.z + c.w * v.w;
  }
  float rea = expf(d0) * a0 + expf(d1) * a1;
  float sc = rea;
#pragma unroll
  for (int d = 1; d < 64; d <<= 1) {
    float o = __shfl_up(sc, d);
    if (lane >= d) sc += o;
  }
  float cum = prefix + sc;
  unsigned long long m2 = __ballot(cum > rtgt);
  int estar = (m2 == 0ull) ? 63 : (int)__builtin_ctzll(m2);
  float p = __shfl(rea, estar);
  if (lane == 0) {
    int sel = cstar * CHUNK_E + estar;
    out[b]     = (float)sel;
    out[B + b] = logf(p);
  }
}

// ---------------------------------------------------------------------------
extern "C" void kernel_launch(void* const* d_in, const int* in_sizes, int n_in,
                              void* d_out, int out_size, void* d_ws, size_t ws_size,
                              hipStream_t stream)
{
  (void)in_sizes; (void)n_in; (void)out_size; (void)ws_size;
  const float* x      = (const float*)d_in[0];
  const float* re     = (const float*)d_in[1];
  const float* rnd    = (const float*)d_in[2];
  const float* gate_w = (const float*)d_in[3];
  const float* gate_b = (const float*)d_in[4];
  const float* Uw     = (const float*)d_in[5];
  const float* Ub     = (const float*)d_in[6];
  const float* Vw     = (const float*)d_in[7];
  const float* Vb     = (const float*)d_in[8];
  char* ws = (char*)d_ws;
  int*    counts  = (int*)(ws + WS_COUNTS);
  int*    cursors = (int*)(ws + WS_CURSORS);
  float*  ps      = (float*)(ws + WS_PS);
  int*    offsets = (int*)(ws + WS_OFFSETS);
  int2*   top2    = (int2*)(ws + WS_TOP2);
  float2* gwv     = (float2*)(ws + WS_GW);
  int*    list    = (int*)(ws + WS_LIST);
  float*  evn     = (float*)(ws + WS_EVN);
  float*  xun     = (float*)(ws + WS_XUN);
  float*  Cc      = (float*)(ws + WS_C);
  float* out = (float*)d_out;

  hipMemsetAsync(ws, 0, 256, stream);
  k_gate   <<<256,  256, 0, stream>>>(x, gate_w, gate_b, top2, gwv, counts, ps);
  k_combine<<<1,    64,  0, stream>>>(counts, ps, offsets, out + 2 * B);
  k_scatter<<<32,   256, 0, stream>>>(top2, offsets, cursors, list);
  k_evn    <<<128,  256, 0, stream>>>(re, Vw, Vb, evn);
  k_xun    <<<1024, 256, 0, stream>>>(x, Uw, Ub, list, counts, offsets, xun);
  k_pass1  <<<1024, 256, 0, stream>>>(evn, xun, list, counts, offsets, Cc);
  k_pass2  <<<2048, 256, 0, stream>>>(evn, xun, Cc, top2, gwv, rnd, out);
}

// Round 5
// 213.027 us; speedup vs baseline: 1.8949x; 1.4376x over previous
//
#include <hip/hip_runtime.h>
#include <math.h>

// Problem constants
#define B 8192
#define E 1024
#define D 384
#define H 64
#define R 8
#define NCHUNK 16
#define CHUNK_E 64

// ws byte offsets (total ~7.6 MB)
#define WS_COUNTS   0u
#define WS_CURSORS  32u
#define WS_PS       64u
#define WS_OFFSETS  96u
#define WS_TOP2     256u      // int2[B]
#define WS_GW       65792u    // float2[B]
#define WS_LIST     131328u   // int[2B]
#define WS_EVN      196864u   // float[R*64*1024]  evnT[r][h][e]  (2 MB)
#define WS_XUN      2294016u  // float[2B*H]       xunP[pos][h]   (4 MB)
#define WS_C        6488320u  // float[2B*16]      C[pos][chunk]  (1 MB)
#define WS_POSMAP   7536896u  // int2[B]           (64 KB)

// ---------------- gate: lane = (sample, router); LDS-transposed gate_w -----
__global__ __launch_bounds__(256) void k_gate(
    const float* __restrict__ x, const float* __restrict__ gate_w,
    const float* __restrict__ gate_b, int2* __restrict__ top2,
    float2* __restrict__ gwv, int* __restrict__ counts, float* __restrict__ ps)
{
  __shared__ __align__(16) float gwT[R * 388];
  __shared__ float psl[R];
  __shared__ int   cl[R];
  int tid = threadIdx.x;
  for (int idx = tid; idx < D * R; idx += 256) {
    int k = idx >> 3, r = idx & 7;
    gwT[r * 388 + k] = gate_w[idx];
  }
  if (tid < R) { psl[tid] = 0.f; cl[tid] = 0; }
  __syncthreads();

  int l = tid & 63;
  int r = tid & 7;
  int b = blockIdx.x * 32 + (tid >> 3);
  float acc = gate_b[r];
  const float4* x4 = (const float4*)(x + (size_t)b * D);
  const float*  gr = gwT + r * 388;
#pragma unroll 4
  for (int q = 0; q < 96; ++q) {
    float4 xv = x4[q];
    float4 gv = *(const float4*)&gr[q * 4];
    acc = fmaf(xv.x, gv.x, acc);
    acc = fmaf(xv.y, gv.y, acc);
    acc = fmaf(xv.z, gv.z, acc);
    acc = fmaf(xv.w, gv.w, acc);
  }
  float lv[R];
#pragma unroll
  for (int rr = 0; rr < R; ++rr) lv[rr] = __shfl(acc, (l & ~7) + rr);
  int i0 = 0; float v0 = lv[0];
#pragma unroll
  for (int rr = 1; rr < R; ++rr) if (lv[rr] > v0) { v0 = lv[rr]; i0 = rr; }
  int i1 = (i0 == 0) ? 1 : 0; float v1 = lv[i1];
#pragma unroll
  for (int rr = 0; rr < R; ++rr)
    if (rr != i0 && lv[rr] > v1) { v1 = lv[rr]; i1 = rr; }
  float se = 0.f;
#pragma unroll
  for (int rr = 0; rr < R; ++rr) se += expf(lv[rr] - v0);
  float p = expf(acc - v0) / se;
  if (r == 0) {
    float e10 = expf(v1 - v0);
    top2[b] = make_int2(i0, i1);
    gwv[b]  = make_float2(1.f / (1.f + e10), e10 / (1.f + e10));
  }
  float pa = p;
  int   ca = (r == i0 ? 1 : 0) + (r == i1 ? 1 : 0);
#pragma unroll
  for (int m = 8; m < 64; m <<= 1) {
    pa += __shfl_xor(pa, m);
    ca += __shfl_xor(ca, m);
  }
  if (l < 8) { atomicAdd(&psl[r], pa); atomicAdd(&cl[r], ca); }
  __syncthreads();
  if (tid < R) { atomicAdd(&ps[tid], psl[tid]); atomicAdd(&counts[tid], cl[tid]); }
}

// ---------------- offsets scan + aux loss ----------------------------------
__global__ void k_combine(const int* __restrict__ counts, const float* __restrict__ ps,
                          int* __restrict__ offsets, float* __restrict__ out_aux)
{
  if (threadIdx.x == 0 && blockIdx.x == 0) {
    int off = 0; float s = 0.f;
    for (int r = 0; r < R; ++r) {
      offsets[r] = off; off += counts[r];
      s += (ps[r] / (float)B) * ((float)counts[r] / (float)B);
    }
    out_aux[0] = (float)R * s * 0.05f;
  }
}

// ---------------- scatter: per-router lists + posmap -----------------------
__global__ __launch_bounds__(256) void k_scatter(
    const int2* __restrict__ top2, const int* __restrict__ offsets,
    int* __restrict__ cursors, int* __restrict__ list, int2* __restrict__ posmap)
{
  __shared__ int lc[R];
  __shared__ int lbase[R];
  int tid = threadIdx.x;
  if (tid < R) lc[tid] = 0;
  __syncthreads();
  int b = min(blockIdx.x * 256 + tid, B - 1);
  int2 t = top2[b];
  t.x &= 7; t.y &= 7;
  int p0 = atomicAdd(&lc[t.x], 1);
  int p1 = atomicAdd(&lc[t.y], 1);
  __syncthreads();
  if (tid < R) lbase[tid] = atomicAdd(&cursors[tid], lc[tid]);
  __syncthreads();
  int i0 = min(offsets[t.x] + lbase[t.x] + p0, 2 * B - 1);
  int i1 = min(offsets[t.y] + lbase[t.y] + p1, 2 * B - 1);
  list[i0] = b * 2 + 0;
  list[i1] = b * 2 + 1;
  posmap[b] = make_int2(i0, i1);
}

// ---------------- evn: GEMM-tiled l2norm -> TRANSPOSED evnT[r][h][e] -------
__global__ __launch_bounds__(256) void k_evn(
    const float* __restrict__ re, const float* __restrict__ Vw,
    const float* __restrict__ Vb, float* __restrict__ evnT)
{
  __shared__ __align__(16) float At[64 * 64];
  __shared__ __align__(16) float Wt[64 * 64];
  int tid = threadIdx.x;
  int rg0 = blockIdx.x * 64;
  int r = rg0 >> 10;
  int e0 = rg0 & 1023;
  int tc = tid & 15, tr = tid >> 4;
  float4 vb = *(const float4*)(Vb + r * H + tc * 4);
  float acc[4][4];   // [i: e-row][j: h-col]
#pragma unroll
  for (int i = 0; i < 4; ++i) { acc[i][0] = vb.x; acc[i][1] = vb.y; acc[i][2] = vb.z; acc[i][3] = vb.w; }

  int arow = tid >> 2, ac = tid & 3;
  const float4* Asrc = (const float4*)re + (size_t)(e0 + arow) * 96;
  const float4* Wsrc = (const float4*)Vw + (size_t)r * 6144;

  for (int kt = 0; kt < 6; ++kt) {
    __syncthreads();
#pragma unroll
    for (int i = 0; i < 4; ++i) {
      float4 v = Asrc[kt * 16 + ac + 4 * i];
      int colb = (ac + 4 * i) * 4;
#pragma unroll
      for (int m = 0; m < 4; ++m) {
        int col = colb + m;
        At[col * 64 + (arow ^ ((col & 15) << 2))] = ((const float*)&v)[m];
      }
    }
#pragma unroll
    for (int i = 0; i < 4; ++i) {
      int idx = tid + 256 * i;
      *(float4*)&Wt[idx * 4] = Wsrc[kt * 1024 + idx];
    }
    __syncthreads();
    for (int k = 0; k < 64; ++k) {
      float4 a4 = *(const float4*)&At[k * 64 + ((tr * 4) ^ ((k & 15) << 2))];
      float4 w4 = *(const float4*)&Wt[k * 64 + tc * 4];
      const float* ap = (const float*)&a4;
      const float* wp = (const float*)&w4;
#pragma unroll
      for (int i = 0; i < 4; ++i)
#pragma unroll
        for (int j = 0; j < 4; ++j) acc[i][j] = fmaf(ap[i], wp[j], acc[i][j]);
    }
  }
  // norms per e-row i (reduction over h: in-thread j + xor over tc lanes)
  float rn[4];
#pragma unroll
  for (int i = 0; i < 4; ++i) {
    float ss = 0.f;
#pragma unroll
    for (int j = 0; j < 4; ++j) ss = fmaf(acc[i][j], acc[i][j], ss);
#pragma unroll
    for (int m = 1; m < 16; m <<= 1) ss += __shfl_xor(ss, m);
    rn[i] = 1.f / fmaxf(sqrtf(ss), 1e-12f);
  }
  // transposed store: for each h (=tc*4+j), write float4 along e
#pragma unroll
  for (int j = 0; j < 4; ++j) {
    float4 o;
    o.x = acc[0][j] * rn[0]; o.y = acc[1][j] * rn[1];
    o.z = acc[2][j] * rn[2]; o.w = acc[3][j] * rn[3];
    *(float4*)(evnT + ((size_t)(r * 64 + tc * 4 + j) * 1024) + e0 + tr * 4) = o;
  }
}

// ---------------- xun: GEMM-tiled l2norm, stored by list position ----------
__global__ __launch_bounds__(256) void k_xun(
    const float* __restrict__ x, const float* __restrict__ Uw,
    const float* __restrict__ Ub, const int* __restrict__ list,
    const int* __restrict__ counts, const int* __restrict__ offsets,
    float* __restrict__ xunP)
{
  int r = blockIdx.x >> 7;
  int tile = blockIdx.x & 127;
  int cnt = min(counts[r], B);
  if (cnt <= 0 || tile * 64 >= cnt) return;
  int n = min(64, cnt - tile * 64);
  int base = offsets[r] + tile * 64;

  __shared__ __align__(16) float At[64 * 64];
  __shared__ __align__(16) float Wt[64 * 64];
  int tid = threadIdx.x;
  int tc = tid & 15, tr = tid >> 4;
  float4 ub = *(const float4*)(Ub + r * H + tc * 4);
  float acc[4][4];
#pragma unroll
  for (int i = 0; i < 4; ++i) { acc[i][0] = ub.x; acc[i][1] = ub.y; acc[i][2] = ub.z; acc[i][3] = ub.w; }

  int arow = tid >> 2, ac = tid & 3;
  int ga = list[min(base + min(arow, n - 1), 2 * B - 1)] & (2 * B - 1);
  const float4* Asrc = (const float4*)x + (size_t)(ga >> 1) * 96;
  const float4* Wsrc = (const float4*)Uw + (size_t)r * 6144;

  for (int kt = 0; kt < 6; ++kt) {
    __syncthreads();
#pragma unroll
    for (int i = 0; i < 4; ++i) {
      float4 v = Asrc[kt * 16 + ac + 4 * i];
      int colb = (ac + 4 * i) * 4;
#pragma unroll
      for (int m = 0; m < 4; ++m) {
        int col = colb + m;
        At[col * 64 + (arow ^ ((col & 15) << 2))] = ((const float*)&v)[m];
      }
    }
#pragma unroll
    for (int i = 0; i < 4; ++i) {
      int idx = tid + 256 * i;
      *(float4*)&Wt[idx * 4] = Wsrc[kt * 1024 + idx];
    }
    __syncthreads();
    for (int k = 0; k < 64; ++k) {
      float4 a4 = *(const float4*)&At[k * 64 + ((tr * 4) ^ ((k & 15) << 2))];
      float4 w4 = *(const float4*)&Wt[k * 64 + tc * 4];
      const float* ap = (const float*)&a4;
      const float* wp = (const float*)&w4;
#pragma unroll
      for (int i = 0; i < 4; ++i)
#pragma unroll
        for (int j = 0; j < 4; ++j) acc[i][j] = fmaf(ap[i], wp[j], acc[i][j]);
    }
  }
#pragma unroll
  for (int i = 0; i < 4; ++i) {
    int row = tr * 4 + i;
    float ss = 0.f;
#pragma unroll
    for (int j = 0; j < 4; ++j) ss = fmaf(acc[i][j], acc[i][j], ss);
#pragma unroll
    for (int m = 1; m < 16; m <<= 1) ss += __shfl_xor(ss, m);
    float rn = 1.f / fmaxf(sqrtf(ss), 1e-12f);
    if (row < n) {
      float4 o; o.x = acc[i][0] * rn; o.y = acc[i][1] * rn; o.z = acc[i][2] * rn; o.w = acc[i][3] * rn;
      *(float4*)(xunP + (size_t)(base + row) * H + tc * 4) = o;
    }
  }
}

// ---------------- pass1: grouped scores GEMM -> exp -> chunk sums ----------
// tile: 128 pos x 64 e (= 1 chunk); LDS Xt[k][s] 32 KB + Et[k][e] 16 KB.
// hot loop: 3x ds_read_b128 + 32 FMA per k-step. grid 8192 (r x stile x et).
__global__ __launch_bounds__(256) void k_pass1(
    const float* __restrict__ evnT, const float* __restrict__ xunP,
    const int* __restrict__ counts, const int* __restrict__ offsets,
    float* __restrict__ C)
{
  int bid = blockIdx.x;
  int et    = bid & 15;
  int stile = (bid >> 4) & 63;
  int r     = bid >> 10;
  int cnt = min(counts[r], B);
  if (cnt <= 0 || stile * 128 >= cnt) return;
  int off = offsets[r] + stile * 128;
  int n = min(128, cnt - stile * 128);
  int ebase = et * 64;

  __shared__ __align__(16) float Xt[64 * 128];
  __shared__ __align__(16) float Et[64 * 64];
  int tid = threadIdx.x;

  {  // Xt: transpose-stage from xunP rows [pos][h] -> [h][s]
    int row = tid >> 1;
    int rc  = min(row, n - 1);
    const float4* src = (const float4*)(xunP + (size_t)(off + rc) * H);
    int hq0 = (tid & 1) * 8;
#pragma unroll
    for (int q = 0; q < 8; ++q) {
      float4 v = src[hq0 + q];
      int h = (hq0 + q) * 4;
      Xt[(h + 0) * 128 + row] = v.x;
      Xt[(h + 1) * 128 + row] = v.y;
      Xt[(h + 2) * 128 + row] = v.z;
      Xt[(h + 3) * 128 + row] = v.w;
    }
  }
  {  // Et: direct copy from evnT [h][ebase..ebase+64)
#pragma unroll
    for (int q = 0; q < 4; ++q) {
      int idx = tid + 256 * q;
      int h = idx >> 4, e4 = idx & 15;
      float4 v = *(const float4*)(evnT + (size_t)(r * 64 + h) * 1024 + ebase + e4 * 4);
      *(float4*)&Et[h * 64 + e4 * 4] = v;
    }
  }
  __syncthreads();

  int sg = tid >> 4, egr = tid & 15;
  float acc[8][4];
#pragma unroll
  for (int i = 0; i < 8; ++i)
#pragma unroll
    for (int j = 0; j < 4; ++j) acc[i][j] = 0.f;

#pragma unroll 4
  for (int k = 0; k < 64; ++k) {
    float4 xa = *(const float4*)&Xt[k * 128 + sg * 8];
    float4 xb = *(const float4*)&Xt[k * 128 + sg * 8 + 4];
    float4 ev = *(const float4*)&Et[k * 64 + egr * 4];
    const float* ep = (const float*)&ev;
    const float* pa = (const float*)&xa;
    const float* pb = (const float*)&xb;
#pragma unroll
    for (int i = 0; i < 4; ++i)
#pragma unroll
      for (int j = 0; j < 4; ++j) {
        acc[i][j]     = fmaf(pa[i], ep[j], acc[i][j]);
        acc[i + 4][j] = fmaf(pb[i], ep[j], acc[i + 4][j]);
      }
  }

#pragma unroll
  for (int i = 0; i < 8; ++i) {
    float v = expf(acc[i][0]) + expf(acc[i][1]) + expf(acc[i][2]) + expf(acc[i][3]);
#pragma unroll
    for (int m = 1; m < 16; m <<= 1) v += __shfl_xor(v, m);
    int s = sg * 8 + i;
    if (egr == 0 && s < n) C[(size_t)(off + s) * NCHUNK + et] = v;
  }
}

// ---------------- pass2: chunk-level inverse-CDF, recompute 1 chunk --------
__global__ __launch_bounds__(256) void k_pass2(
    const float* __restrict__ evnT, const float* __restrict__ xunP,
    const float* __restrict__ C, const int2* __restrict__ top2,
    const int2* __restrict__ posmap, const float2* __restrict__ gwv,
    const float* __restrict__ rnd, float* __restrict__ out)
{
  int tid = threadIdx.x;
  int lane = tid & 63;
  int b = blockIdx.x * 4 + (tid >> 6);
  if (b >= B) return;
  int2 t2 = top2[b];
  t2.x &= 7; t2.y &= 7;
  int2 pm = posmap[b];
  pm.x &= (2 * B - 1); pm.y &= (2 * B - 1);
  float2 gw = gwv[b];
  float rv = rnd[b];

  // phase 1: redundant per-lane chunk CDF
  const float4* C04 = (const float4*)(C + (size_t)pm.x * NCHUNK);
  const float4* C14 = (const float4*)(C + (size_t)pm.y * NCHUNK);
  float c0[NCHUNK], c1[NCHUNK];
#pragma unroll
  for (int q = 0; q < 4; ++q) {
    float4 v0 = C04[q], v1 = C14[q];
    c0[q*4+0]=v0.x; c0[q*4+1]=v0.y; c0[q*4+2]=v0.z; c0[q*4+3]=v0.w;
    c1[q*4+0]=v1.x; c1[q*4+1]=v1.y; c1[q*4+2]=v1.z; c1[q*4+3]=v1.w;
  }
  float S0 = 0.f, S1 = 0.f;
#pragma unroll
  for (int j = 0; j < NCHUNK; ++j) { S0 += c0[j]; S1 += c1[j]; }
  float a0 = gw.x / S0, a1 = gw.y / S1;
  int cstar = -1; float prefix = 0.f; float run = 0.f;
#pragma unroll
  for (int j = 0; j < NCHUNK; ++j) {
    float nrun = run + (c0[j] * a0 + c1[j] * a1);
    if (cstar < 0 && nrun > rv) { cstar = j; prefix = run; }
    run = nrun;
  }
  float rtgt = rv;
  if (cstar < 0) { cstar = 0; prefix = 0.f; rtgt = -1.0f; }

  // phase 2: recompute chunk cstar; lane = local e; coalesced evnT reads
  float xu0 = xunP[(size_t)pm.x * H + lane];
  float xu1 = xunP[(size_t)pm.y * H + lane];
  const float* E0 = evnT + (size_t)t2.x * 64 * 1024 + cstar * CHUNK_E + lane;
  const float* E1 = evnT + (size_t)t2.y * 64 * 1024 + cstar * CHUNK_E + lane;
  float d0 = 0.f, d1 = 0.f;
#pragma unroll 16
  for (int h = 0; h < 64; ++h) {
    float w0 = __shfl(xu0, h);
    float w1 = __shfl(xu1, h);
    d0 = fmaf(E0[(size_t)h * 1024], w0, d0);
    d1 = fmaf(E1[(size_t)h * 1024], w1, d1);
  }
  float rea = expf(d0) * a0 + expf(d1) * a1;
  float sc = rea;
#pragma unroll
  for (int d = 1; d < 64; d <<= 1) {
    float o = __shfl_up(sc, d);
    if (lane >= d) sc += o;
  }
  float cum = prefix + sc;
  unsigned long long m2 = __ballot(cum > rtgt);
  int estar = (m2 == 0ull) ? 63 : (int)__builtin_ctzll(m2);
  float p = __shfl(rea, estar);
  if (lane == 0) {
    int sel = cstar * CHUNK_E + estar;
    out[b]     = (float)sel;
    out[B + b] = logf(p);
  }
}

// ---------------------------------------------------------------------------
extern "C" void kernel_launch(void* const* d_in, const int* in_sizes, int n_in,
                              void* d_out, int out_size, void* d_ws, size_t ws_size,
                              hipStream_t stream)
{
  (void)in_sizes; (void)n_in; (void)out_size; (void)ws_size;
  const float* x      = (const float*)d_in[0];
  const float* re     = (const float*)d_in[1];
  const float* rnd    = (const float*)d_in[2];
  const float* gate_w = (const float*)d_in[3];
  const float* gate_b = (const float*)d_in[4];
  const float* Uw     = (const float*)d_in[5];
  const float* Ub     = (const float*)d_in[6];
  const float* Vw     = (const float*)d_in[7];
  const float* Vb     = (const float*)d_in[8];
  char* ws = (char*)d_ws;
  int*    counts  = (int*)(ws + WS_COUNTS);
  int*    cursors = (int*)(ws + WS_CURSORS);
  float*  ps      = (float*)(ws + WS_PS);
  int*    offsets = (int*)(ws + WS_OFFSETS);
  int2*   top2    = (int2*)(ws + WS_TOP2);
  float2* gwv     = (float2*)(ws + WS_GW);
  int*    list    = (int*)(ws + WS_LIST);
  float*  evnT    = (float*)(ws + WS_EVN);
  float*  xunP    = (float*)(ws + WS_XUN);
  float*  Cc      = (float*)(ws + WS_C);
  int2*   posmap  = (int2*)(ws + WS_POSMAP);
  float* out = (float*)d_out;

  hipMemsetAsync(ws, 0, 256, stream);
  k_gate   <<<256,  256, 0, stream>>>(x, gate_w, gate_b, top2, gwv, counts, ps);
  k_combine<<<1,    64,  0, stream>>>(counts, ps, offsets, out + 2 * B);
  k_scatter<<<32,   256, 0, stream>>>(top2, offsets, cursors, list, posmap);
  k_evn    <<<128,  256, 0, stream>>>(re, Vw, Vb, evnT);
  k_xun    <<<1024, 256, 0, stream>>>(x, Uw, Ub, list, counts, offsets, xunP);
  k_pass1  <<<8192, 256, 0, stream>>>(evnT, xunP, counts, offsets, Cc);
  k_pass2  <<<2048, 256, 0, stream>>>(evnT, xunP, Cc, top2, posmap, gwv, rnd, out);
}

// Round 6
// 184.690 us; speedup vs baseline: 2.1856x; 1.1534x over previous
//
#include <hip/hip_runtime.h>
#include <math.h>

// Problem constants
#define B 8192
#define E 1024
#define D 384
#define H 64
#define R 8
#define NCHUNK 16
#define CHUNK_E 64

// ws byte offsets (total ~7.6 MB)
#define WS_COUNTS   0u
#define WS_CURSORS  32u
#define WS_PS       64u
#define WS_TOP2     256u      // int2[B]
#define WS_GW       65792u    // float2[B]
#define WS_LIST     131328u   // int[2B]
#define WS_EVN      196864u   // float[R*64*1024]  evnT[r][h][e]  (2 MB)
#define WS_XUN      2294016u  // float[2B*H]       xunP[pos][h]   (4 MB)
#define WS_C        6488320u  // float[2B*16]      C[pos][chunk]  (1 MB)
#define WS_POSMAP   7536896u  // int2[B]           (64 KB)

// ---------------- gate: lane = (sample, router); LDS-transposed gate_w -----
__global__ __launch_bounds__(256) void k_gate(
    const float* __restrict__ x, const float* __restrict__ gate_w,
    const float* __restrict__ gate_b, int2* __restrict__ top2,
    float2* __restrict__ gwv, int* __restrict__ counts, float* __restrict__ ps)
{
  __shared__ __align__(16) float gwT[R * 388];
  __shared__ float psl[R];
  __shared__ int   cl[R];
  int tid = threadIdx.x;
  for (int idx = tid; idx < D * R; idx += 256) {
    int k = idx >> 3, r = idx & 7;
    gwT[r * 388 + k] = gate_w[idx];
  }
  if (tid < R) { psl[tid] = 0.f; cl[tid] = 0; }
  __syncthreads();

  int l = tid & 63;
  int r = tid & 7;
  int b = blockIdx.x * 32 + (tid >> 3);
  float acc = gate_b[r];
  const float4* x4 = (const float4*)(x + (size_t)b * D);
  const float*  gr = gwT + r * 388;
#pragma unroll 4
  for (int q = 0; q < 96; ++q) {
    float4 xv = x4[q];
    float4 gv = *(const float4*)&gr[q * 4];
    acc = fmaf(xv.x, gv.x, acc);
    acc = fmaf(xv.y, gv.y, acc);
    acc = fmaf(xv.z, gv.z, acc);
    acc = fmaf(xv.w, gv.w, acc);
  }
  float lv[R];
#pragma unroll
  for (int rr = 0; rr < R; ++rr) lv[rr] = __shfl(acc, (l & ~7) + rr);
  int i0 = 0; float v0 = lv[0];
#pragma unroll
  for (int rr = 1; rr < R; ++rr) if (lv[rr] > v0) { v0 = lv[rr]; i0 = rr; }
  int i1 = (i0 == 0) ? 1 : 0; float v1 = lv[i1];
#pragma unroll
  for (int rr = 0; rr < R; ++rr)
    if (rr != i0 && lv[rr] > v1) { v1 = lv[rr]; i1 = rr; }
  float se = 0.f;
#pragma unroll
  for (int rr = 0; rr < R; ++rr) se += expf(lv[rr] - v0);
  float p = expf(acc - v0) / se;
  if (r == 0) {
    float e10 = expf(v1 - v0);
    top2[b] = make_int2(i0, i1);
    gwv[b]  = make_float2(1.f / (1.f + e10), e10 / (1.f + e10));
  }
  float pa = p;
  int   ca = (r == i0 ? 1 : 0) + (r == i1 ? 1 : 0);
#pragma unroll
  for (int m = 8; m < 64; m <<= 1) {
    pa += __shfl_xor(pa, m);
    ca += __shfl_xor(ca, m);
  }
  if (l < 8) { atomicAdd(&psl[r], pa); atomicAdd(&cl[r], ca); }
  __syncthreads();
  if (tid < R) { atomicAdd(&ps[tid], psl[tid]); atomicAdd(&counts[tid], cl[tid]); }
}

// ---------------- scatter: per-router lists + posmap + aux loss ------------
__global__ __launch_bounds__(256) void k_scatter(
    const int2* __restrict__ top2, const int* __restrict__ counts,
    const float* __restrict__ ps, int* __restrict__ cursors,
    int* __restrict__ list, int2* __restrict__ posmap, float* __restrict__ out_aux)
{
  __shared__ int lc[R];
  __shared__ int lbase[R];
  __shared__ int offs[R];
  int tid = threadIdx.x;
  if (tid < R) { lc[tid] = 0; offs[tid] = min(counts[tid], B); }
  __syncthreads();
  if (tid == 0) {
    int o = 0;
    for (int r2 = 0; r2 < R; ++r2) { int c = offs[r2]; offs[r2] = o; o += c; }
  }
  __syncthreads();
  int b = min(blockIdx.x * 256 + tid, B - 1);
  int2 t = top2[b];
  t.x &= 7; t.y &= 7;
  int p0 = atomicAdd(&lc[t.x], 1);
  int p1 = atomicAdd(&lc[t.y], 1);
  __syncthreads();
  if (tid < R) lbase[tid] = atomicAdd(&cursors[tid], lc[tid]);
  __syncthreads();
  int i0 = min(offs[t.x] + lbase[t.x] + p0, 2 * B - 1);
  int i1 = min(offs[t.y] + lbase[t.y] + p1, 2 * B - 1);
  list[i0] = b * 2 + 0;
  list[i1] = b * 2 + 1;
  posmap[b] = make_int2(i0, i1);
  if (blockIdx.x == 0 && tid == 0) {
    float s = 0.f;
    for (int r2 = 0; r2 < R; ++r2)
      s += (ps[r2] / (float)B) * ((float)min(counts[r2], B) / (float)B);
    out_aux[0] = (float)R * s * 0.05f;
  }
}

// ---------------- proj: unified evn + xun projection + l2norm --------------
// 32-row x 64-h tiles, 128 threads, 4x4 per thread. LDS: At[k][row] 8 KB +
// Wt[k][h] 16 KB, all accesses conflict-free (<=2-way) by construction.
// grid: [0,256) = evn tiles (r = bid>>5, e0 = (bid&31)*32);
//       [256, 256+2048) = xun tiles (r = idx>>8, row0 = (idx&255)*32).
__global__ __launch_bounds__(128) void k_proj(
    const float* __restrict__ re, const float* __restrict__ x,
    const float* __restrict__ Vw, const float* __restrict__ Vb,
    const float* __restrict__ Uw, const float* __restrict__ Ub,
    const int* __restrict__ list, const int* __restrict__ counts,
    float* __restrict__ evnT, float* __restrict__ xunP)
{
  __shared__ __align__(16) float At[64 * 32];   // [k][row]
  __shared__ __align__(16) float Wt[64 * 64];   // [k][h]
  __shared__ int cntL[R];
  int tid = threadIdx.x;
  int bid = blockIdx.x;
  if (tid < R) cntL[tid] = min(counts[tid], B);
  __syncthreads();

  bool isE = (bid < 256);
  int r, row0, n, base = 0;
  const float* Wsrc; const float* bias;
  if (isE) {
    r = bid >> 5; row0 = (bid & 31) * 32; n = 32;
    Wsrc = Vw + (size_t)r * D * H; bias = Vb + r * H;
  } else {
    int idx = bid - 256;
    r = idx >> 8; row0 = (idx & 255) * 32;
    int cnt = cntL[r];
    if (row0 >= cnt) return;
    n = min(32, cnt - row0);
    for (int rr = 0; rr < r; ++rr) base += cntL[rr];
    base += row0;
    Wsrc = Uw + (size_t)r * D * H; bias = Ub + r * H;
  }

  // staging roles
  int rowS = tid & 31, kq = tid >> 5;           // kq in 0..3
  const float4* Arow;
  if (isE) {
    Arow = (const float4*)re + (size_t)(row0 + rowS) * 96;
  } else {
    int g = list[min(base + min(rowS, n - 1), 2 * B - 1)] & (2 * B - 1);
    Arow = (const float4*)x + (size_t)(g >> 1) * 96;
  }
  const float4* W4 = (const float4*)Wsrc;

  // compute roles
  int rg = tid >> 4;        // 0..7 (4 rows each)
  int hg = tid & 15;        // 0..15 (4 h each)
  float4 bv = *(const float4*)(bias + hg * 4);
  float acc[4][4];
#pragma unroll
  for (int i = 0; i < 4; ++i) {
    acc[i][0] = bv.x; acc[i][1] = bv.y; acc[i][2] = bv.z; acc[i][3] = bv.w;
  }

  for (int kt = 0; kt < 6; ++kt) {
    __syncthreads();
#pragma unroll
    for (int q = 0; q < 4; ++q) {               // A: [row][k] -> [k][row]
      float4 v = Arow[kt * 16 + kq + 4 * q];
      int kb = (kq + 4 * q) * 4;
      At[(kb + 0) * 32 + rowS] = v.x;
      At[(kb + 1) * 32 + rowS] = v.y;
      At[(kb + 2) * 32 + rowS] = v.z;
      At[(kb + 3) * 32 + rowS] = v.w;
    }
#pragma unroll
    for (int q = 0; q < 8; ++q) {               // W: direct [k][h] copy
      int idx2 = tid + 128 * q;
      int k = idx2 >> 4, h4 = idx2 & 15;
      *(float4*)&Wt[k * 64 + h4 * 4] = W4[(size_t)(kt * 64 + k) * 16 + h4];
    }
    __syncthreads();
#pragma unroll 8
    for (int k = 0; k < 64; ++k) {
      float4 a4 = *(const float4*)&At[k * 32 + rg * 4];
      float4 w4 = *(const float4*)&Wt[k * 64 + hg * 4];
      const float* ap = (const float*)&a4;
      const float* wp = (const float*)&w4;
#pragma unroll
      for (int i = 0; i < 4; ++i)
#pragma unroll
        for (int j = 0; j < 4; ++j) acc[i][j] = fmaf(ap[i], wp[j], acc[i][j]);
    }
  }

  // row norms: in-thread over j, cross-lane over hg (bits 0..3 of lane)
  float rn[4];
#pragma unroll
  for (int i = 0; i < 4; ++i) {
    float ss = 0.f;
#pragma unroll
    for (int j = 0; j < 4; ++j) ss = fmaf(acc[i][j], acc[i][j], ss);
#pragma unroll
    for (int m = 1; m < 16; m <<= 1) ss += __shfl_xor(ss, m);
    rn[i] = 1.f / fmaxf(sqrtf(ss), 1e-12f);
  }

  if (isE) {
    // transposed store: float4 along e for each of this thread's 4 h
#pragma unroll
    for (int j = 0; j < 4; ++j) {
      float4 o;
      o.x = acc[0][j] * rn[0]; o.y = acc[1][j] * rn[1];
      o.z = acc[2][j] * rn[2]; o.w = acc[3][j] * rn[3];
      *(float4*)(evnT + (size_t)(r * 64 + hg * 4 + j) * 1024 + row0 + rg * 4) = o;
    }
  } else {
#pragma unroll
    for (int i = 0; i < 4; ++i) {
      int row = rg * 4 + i;
      if (row < n) {
        float4 o;
        o.x = acc[i][0] * rn[i]; o.y = acc[i][1] * rn[i];
        o.z = acc[i][2] * rn[i]; o.w = acc[i][3] * rn[i];
        *(float4*)(xunP + (size_t)(base + row) * H + hg * 4) = o;
      }
    }
  }
}

// ---------------- pass1: grouped scores GEMM -> exp -> chunk sums ----------
// tile: 128 pos x 64 e (= 1 chunk); LDS Xt[k][s] 32 KB + Et[k][e] 16 KB.
__global__ __launch_bounds__(256) void k_pass1(
    const float* __restrict__ evnT, const float* __restrict__ xunP,
    const int* __restrict__ counts, float* __restrict__ C)
{
  __shared__ __align__(16) float Xt[64 * 128];
  __shared__ __align__(16) float Et[64 * 64];
  __shared__ int cntL[R];
  int tid = threadIdx.x;
  if (tid < R) cntL[tid] = min(counts[tid], B);
  __syncthreads();

  int bid = blockIdx.x;
  int et    = bid & 15;
  int stile = (bid >> 4) & 63;
  int r     = bid >> 10;
  int cnt = cntL[r];
  if (cnt <= 0 || stile * 128 >= cnt) return;
  int off = 0;
  for (int rr = 0; rr < r; ++rr) off += cntL[rr];
  off += stile * 128;
  int n = min(128, cnt - stile * 128);
  int ebase = et * 64;

  {  // Xt: transpose-stage from xunP rows [pos][h] -> [h][s]
    int row = tid >> 1;
    int rc  = min(row, n - 1);
    const float4* src = (const float4*)(xunP + (size_t)(off + rc) * H);
    int hq0 = (tid & 1) * 8;
#pragma unroll
    for (int q = 0; q < 8; ++q) {
      float4 v = src[hq0 + q];
      int h = (hq0 + q) * 4;
      Xt[(h + 0) * 128 + row] = v.x;
      Xt[(h + 1) * 128 + row] = v.y;
      Xt[(h + 2) * 128 + row] = v.z;
      Xt[(h + 3) * 128 + row] = v.w;
    }
  }
  {  // Et: direct copy from evnT [h][ebase..ebase+64)
#pragma unroll
    for (int q = 0; q < 4; ++q) {
      int idx = tid + 256 * q;
      int h = idx >> 4, e4 = idx & 15;
      float4 v = *(const float4*)(evnT + (size_t)(r * 64 + h) * 1024 + ebase + e4 * 4);
      *(float4*)&Et[h * 64 + e4 * 4] = v;
    }
  }
  __syncthreads();

  int sg = tid >> 4, egr = tid & 15;
  float acc[8][4];
#pragma unroll
  for (int i = 0; i < 8; ++i)
#pragma unroll
    for (int j = 0; j < 4; ++j) acc[i][j] = 0.f;

#pragma unroll 4
  for (int k = 0; k < 64; ++k) {
    float4 xa = *(const float4*)&Xt[k * 128 + sg * 8];
    float4 xb = *(const float4*)&Xt[k * 128 + sg * 8 + 4];
    float4 ev = *(const float4*)&Et[k * 64 + egr * 4];
    const float* ep = (const float*)&ev;
    const float* pa = (const float*)&xa;
    const float* pb = (const float*)&xb;
#pragma unroll
    for (int i = 0; i < 4; ++i)
#pragma unroll
      for (int j = 0; j < 4; ++j) {
        acc[i][j]     = fmaf(pa[i], ep[j], acc[i][j]);
        acc[i + 4][j] = fmaf(pb[i], ep[j], acc[i + 4][j]);
      }
  }

#pragma unroll
  for (int i = 0; i < 8; ++i) {
    float v = expf(acc[i][0]) + expf(acc[i][1]) + expf(acc[i][2]) + expf(acc[i][3]);
#pragma unroll
    for (int m = 1; m < 16; m <<= 1) v += __shfl_xor(v, m);
    int s = sg * 8 + i;
    if (egr == 0 && s < n) C[(size_t)(off + s) * NCHUNK + et] = v;
  }
}

// ---------------- pass2: chunk-level inverse-CDF, recompute 1 chunk --------
__global__ __launch_bounds__(256) void k_pass2(
    const float* __restrict__ evnT, const float* __restrict__ xunP,
    const float* __restrict__ C, const int2* __restrict__ top2,
    const int2* __restrict__ posmap, const float2* __restrict__ gwv,
    const float* __restrict__ rnd, float* __restrict__ out)
{
  int tid = threadIdx.x;
  int lane = tid & 63;
  int b = blockIdx.x * 4 + (tid >> 6);
  if (b >= B) return;
  int2 t2 = top2[b];
  t2.x &= 7; t2.y &= 7;
  int2 pm = posmap[b];
  pm.x &= (2 * B - 1); pm.y &= (2 * B - 1);
  float2 gw = gwv[b];
  float rv = rnd[b];

  // phase 1: redundant per-lane chunk CDF
  const float4* C04 = (const float4*)(C + (size_t)pm.x * NCHUNK);
  const float4* C14 = (const float4*)(C + (size_t)pm.y * NCHUNK);
  float c0[NCHUNK], c1[NCHUNK];
#pragma unroll
  for (int q = 0; q < 4; ++q) {
    float4 v0 = C04[q], v1 = C14[q];
    c0[q*4+0]=v0.x; c0[q*4+1]=v0.y; c0[q*4+2]=v0.z; c0[q*4+3]=v0.w;
    c1[q*4+0]=v1.x; c1[q*4+1]=v1.y; c1[q*4+2]=v1.z; c1[q*4+3]=v1.w;
  }
  float S0 = 0.f, S1 = 0.f;
#pragma unroll
  for (int j = 0; j < NCHUNK; ++j) { S0 += c0[j]; S1 += c1[j]; }
  float a0 = gw.x / S0, a1 = gw.y / S1;
  int cstar = -1; float prefix = 0.f; float run = 0.f;
#pragma unroll
  for (int j = 0; j < NCHUNK; ++j) {
    float nrun = run + (c0[j] * a0 + c1[j] * a1);
    if (cstar < 0 && nrun > rv) { cstar = j; prefix = run; }
    run = nrun;
  }
  float rtgt = rv;
  if (cstar < 0) { cstar = 0; prefix = 0.f; rtgt = -1.0f; }

  // phase 2: recompute chunk cstar; lane = local e; coalesced evnT reads
  float xu0 = xunP[(size_t)pm.x * H + lane];
  float xu1 = xunP[(size_t)pm.y * H + lane];
  const float* E0 = evnT + (size_t)t2.x * 64 * 1024 + cstar * CHUNK_E + lane;
  const float* E1 = evnT + (size_t)t2.y * 64 * 1024 + cstar * CHUNK_E + lane;
  float d0 = 0.f, d1 = 0.f;
#pragma unroll 16
  for (int h = 0; h < 64; ++h) {
    float w0 = __shfl(xu0, h);
    float w1 = __shfl(xu1, h);
    d0 = fmaf(E0[(size_t)h * 1024], w0, d0);
    d1 = fmaf(E1[(size_t)h * 1024], w1, d1);
  }
  float rea = expf(d0) * a0 + expf(d1) * a1;
  float sc = rea;
#pragma unroll
  for (int d = 1; d < 64; d <<= 1) {
    float o = __shfl_up(sc, d);
    if (lane >= d) sc += o;
  }
  float cum = prefix + sc;
  unsigned long long m2 = __ballot(cum > rtgt);
  int estar = (m2 == 0ull) ? 63 : (int)__builtin_ctzll(m2);
  float p = __shfl(rea, estar);
  if (lane == 0) {
    int sel = cstar * CHUNK_E + estar;
    out[b]     = (float)sel;
    out[B + b] = logf(p);
  }
}

// ---------------------------------------------------------------------------
extern "C" void kernel_launch(void* const* d_in, const int* in_sizes, int n_in,
                              void* d_out, int out_size, void* d_ws, size_t ws_size,
                              hipStream_t stream)
{
  (void)in_sizes; (void)n_in; (void)out_size; (void)ws_size;
  const float* x      = (const float*)d_in[0];
  const float* re     = (const float*)d_in[1];
  const float* rnd    = (const float*)d_in[2];
  const float* gate_w = (const float*)d_in[3];
  const float* gate_b = (const float*)d_in[4];
  const float* Uw     = (const float*)d_in[5];
  const float* Ub     = (const float*)d_in[6];
  const float* Vw     = (const float*)d_in[7];
  const float* Vb     = (const float*)d_in[8];
  char* ws = (char*)d_ws;
  int*    counts  = (int*)(ws + WS_COUNTS);
  int*    cursors = (int*)(ws + WS_CURSORS);
  float*  ps      = (float*)(ws + WS_PS);
  int2*   top2    = (int2*)(ws + WS_TOP2);
  float2* gwv     = (float2*)(ws + WS_GW);
  int*    list    = (int*)(ws + WS_LIST);
  float*  evnT    = (float*)(ws + WS_EVN);
  float*  xunP    = (float*)(ws + WS_XUN);
  float*  Cc      = (float*)(ws + WS_C);
  int2*   posmap  = (int2*)(ws + WS_POSMAP);
  float* out = (float*)d_out;

  hipMemsetAsync(ws, 0, 256, stream);
  k_gate   <<<256,  256, 0, stream>>>(x, gate_w, gate_b, top2, gwv, counts, ps);
  k_scatter<<<32,   256, 0, stream>>>(top2, counts, ps, cursors, list, posmap, out + 2 * B);
  k_proj   <<<2304, 128, 0, stream>>>(re, x, Vw, Vb, Uw, Ub, list, counts, evnT, xunP);
  k_pass1  <<<8192, 256, 0, stream>>>(evnT, xunP, counts, Cc);
  k_pass2  <<<2048, 256, 0, stream>>>(evnT, xunP, Cc, top2, posmap, gwv, rnd, out);
}